// Round 4
// baseline (480.190 us; speedup 1.0000x reference)
//
#include <hip/hip_runtime.h>

#define NN 50000
#define EE 800000
#define FIN 128
#define HH 64
#define TT 8
#define GG 64
#define NCONVS 3
#define BN_EPS 1e-5f
#define NB_SCAN 196   // ceil(NN/256)
#define RNODES 128    // nodes per readout block

__device__ __forceinline__ unsigned enc_f32(float x) {
  unsigned u = __float_as_uint(x);
  return (u & 0x80000000u) ? ~u : (u | 0x80000000u);
}
__device__ __forceinline__ float dec_f32(unsigned e) {
  unsigned u = (e & 0x80000000u) ? (e & 0x7fffffffu) : ~e;
  return __uint_as_float(u);
}

// y[N,64] = op(in) @ W[K,64] + bias, with fused per-column BN stats of y.
// MODE 0: raw input (K=FIN)
// MODE 1: relu(in*scale+shift), scale/shift computed from stats_in+gamma/beta
// MODE 2: in[row] + sum_{j in CSR(row)} in[srcs[j]]   (GIN aggregation)
// Each block processes 64 rows (4 chunks of 16); flushes stats once.
template <int K, int MODE>
__global__ __launch_bounds__(256) void mm_stats_kernel(
    const float* __restrict__ in, const int* __restrict__ offs,
    const int* __restrict__ srcs, const float* __restrict__ stats_in,
    const float* __restrict__ gamma, const float* __restrict__ beta,
    const float* __restrict__ W, const float* __restrict__ bias,
    float* __restrict__ y, float* __restrict__ stats_out) {
  __shared__ float Wl[K * HH];
  __shared__ float Al[16][K + 1];
  __shared__ float ssl[128];
  __shared__ float sred[4][128];
  const int t = threadIdx.x;
  {
    const float4* W4 = (const float4*)W;
    float4* Wl4 = (float4*)Wl;
#pragma unroll
    for (int i = 0; i < (K * HH) / 1024; ++i) Wl4[t + i * 256] = W4[t + i * 256];
  }
  if (MODE == 1 && t < 64) {
    const float inv = 1.f / (float)NN;
    const float mean = stats_in[t] * inv;
    const float var = stats_in[64 + t] * inv - mean * mean;
    const float sc = gamma[t] * rsqrtf(var + BN_EPS);
    ssl[t] = sc;
    ssl[64 + t] = fmaf(-mean, sc, beta[t]);
  }
  const int r = t >> 4, g = t & 15;
  const float4 bb = *(const float4*)&bias[g * 4];
  float st_s[4] = {0.f, 0.f, 0.f, 0.f}, st_q[4] = {0.f, 0.f, 0.f, 0.f};
  __syncthreads();

#pragma unroll
  for (int chunk = 0; chunk < 4; ++chunk) {
    const int row = blockIdx.x * 64 + chunk * 16 + r;
    if (row < NN) {
      if (MODE == 0) {
#pragma unroll
        for (int p = 0; p < K / 64; ++p) {
          const int c0 = g * 4 + p * 64;
          const float4 v = *(const float4*)&in[row * K + c0];
          Al[r][c0 + 0] = v.x; Al[r][c0 + 1] = v.y;
          Al[r][c0 + 2] = v.z; Al[r][c0 + 3] = v.w;
        }
      } else if (MODE == 1) {
        const int c0 = g * 4;
        const float4 v = *(const float4*)&in[row * HH + c0];
        Al[r][c0 + 0] = fmaxf(fmaf(v.x, ssl[c0 + 0], ssl[64 + c0 + 0]), 0.f);
        Al[r][c0 + 1] = fmaxf(fmaf(v.y, ssl[c0 + 1], ssl[64 + c0 + 1]), 0.f);
        Al[r][c0 + 2] = fmaxf(fmaf(v.z, ssl[c0 + 2], ssl[64 + c0 + 2]), 0.f);
        Al[r][c0 + 3] = fmaxf(fmaf(v.w, ssl[c0 + 3], ssl[64 + c0 + 3]), 0.f);
      } else {  // MODE 2: GIN aggregate h[row] + sum of neighbors
        const int c0 = g * 4;
        float4 v = *(const float4*)&in[row * HH + c0];
        float4 acc = make_float4(0.f, 0.f, 0.f, 0.f);
        const int s0 = offs[row], s1 = offs[row + 1];
        int j = s0;
        for (; j + 1 < s1; j += 2) {
          const int sA = srcs[j], sB = srcs[j + 1];
          const float4 vA = *(const float4*)&in[sA * HH + c0];
          const float4 vB = *(const float4*)&in[sB * HH + c0];
          v.x += vA.x; v.y += vA.y; v.z += vA.z; v.w += vA.w;
          acc.x += vB.x; acc.y += vB.y; acc.z += vB.z; acc.w += vB.w;
        }
        if (j < s1) {
          const int sA = srcs[j];
          const float4 vA = *(const float4*)&in[sA * HH + c0];
          v.x += vA.x; v.y += vA.y; v.z += vA.z; v.w += vA.w;
        }
        Al[r][c0 + 0] = v.x + acc.x; Al[r][c0 + 1] = v.y + acc.y;
        Al[r][c0 + 2] = v.z + acc.z; Al[r][c0 + 3] = v.w + acc.w;
      }
    } else {
#pragma unroll
      for (int p = 0; p < K / 64; ++p) {
        const int c0 = g * 4 + p * 64;
        Al[r][c0 + 0] = 0.f; Al[r][c0 + 1] = 0.f;
        Al[r][c0 + 2] = 0.f; Al[r][c0 + 3] = 0.f;
      }
    }
    __syncthreads();
    float ax = 0.f, ay = 0.f, az = 0.f, aw = 0.f;
#pragma unroll
    for (int k = 0; k < K; ++k) {
      const float a = Al[r][k];
      const float4 w = *(const float4*)&Wl[k * HH + g * 4];
      ax = fmaf(a, w.x, ax); ay = fmaf(a, w.y, ay);
      az = fmaf(a, w.z, az); aw = fmaf(a, w.w, aw);
    }
    if (row < NN) {
      float4 o;
      o.x = ax + bb.x; o.y = ay + bb.y; o.z = az + bb.z; o.w = aw + bb.w;
      *(float4*)&y[row * HH + g * 4] = o;
      st_s[0] += o.x; st_s[1] += o.y; st_s[2] += o.z; st_s[3] += o.w;
      st_q[0] = fmaf(o.x, o.x, st_q[0]); st_q[1] = fmaf(o.y, o.y, st_q[1]);
      st_q[2] = fmaf(o.z, o.z, st_q[2]); st_q[3] = fmaf(o.w, o.w, st_q[3]);
    }
    __syncthreads();
  }
  // block-level stats reduction: over r (16 rows-slots) then flush
#pragma unroll
  for (int off = 16; off <= 32; off <<= 1) {
#pragma unroll
    for (int i = 0; i < 4; ++i) {
      st_s[i] += __shfl_xor(st_s[i], off);
      st_q[i] += __shfl_xor(st_q[i], off);
    }
  }
  const int wave = t >> 6, lane = t & 63;
  if (lane < 16) {
#pragma unroll
    for (int i = 0; i < 4; ++i) {
      sred[wave][lane * 4 + i] = st_s[i];
      sred[wave][64 + lane * 4 + i] = st_q[i];
    }
  }
  __syncthreads();
  if (t < 128)
    atomicAdd(&stats_out[t],
              sred[0][t] + sred[1][t] + sred[2][t] + sred[3][t]);
}

// ---------------- CSR build ----------------
__global__ __launch_bounds__(256) void hist_kernel(const int* __restrict__ ei,
                                                   int* __restrict__ deg) {
  const int e = blockIdx.x * 256 + threadIdx.x;
  if (e < EE) atomicAdd(&deg[ei[EE + e]], 1);
}

__global__ __launch_bounds__(256) void scan1_kernel(const int* __restrict__ deg,
                                                    int* __restrict__ bsum) {
  __shared__ int s[256];
  const int i = blockIdx.x * 256 + threadIdx.x;
  s[threadIdx.x] = (i < NN) ? deg[i] : 0;
  __syncthreads();
  for (int off = 128; off > 0; off >>= 1) {
    if (threadIdx.x < off) s[threadIdx.x] += s[threadIdx.x + off];
    __syncthreads();
  }
  if (threadIdx.x == 0) bsum[blockIdx.x] = s[0];
}

__global__ void scan2_kernel(int* __restrict__ bsum) {
  __shared__ int s[256];
  const int t = threadIdx.x;
  const int orig = (t < NB_SCAN) ? bsum[t] : 0;
  s[t] = orig;
  __syncthreads();
  for (int off = 1; off < 256; off <<= 1) {
    const int u = (t >= off) ? s[t - off] : 0;
    __syncthreads();
    s[t] += u;
    __syncthreads();
  }
  if (t < NB_SCAN) bsum[t] = s[t] - orig;  // exclusive
}

__global__ __launch_bounds__(256) void scan3_kernel(const int* __restrict__ deg,
                                                    const int* __restrict__ bsum,
                                                    int* __restrict__ offs,
                                                    int* __restrict__ cursor) {
  __shared__ int s[256];
  const int t = threadIdx.x;
  const int i = blockIdx.x * 256 + t;
  const int orig = (i < NN) ? deg[i] : 0;
  s[t] = orig;
  __syncthreads();
  for (int off = 1; off < 256; off <<= 1) {
    const int u = (t >= off) ? s[t - off] : 0;
    __syncthreads();
    s[t] += u;
    __syncthreads();
  }
  const int excl = s[t] - orig + bsum[blockIdx.x];
  if (i < NN) {
    offs[i] = excl;
    cursor[i] = excl;
    if (i == NN - 1) offs[NN] = excl + orig;
  }
}

__global__ __launch_bounds__(256) void fill_kernel(const int* __restrict__ ei,
                                                   int* __restrict__ cursor,
                                                   int* __restrict__ srcs) {
  const int e = blockIdx.x * 256 + threadIdx.x;
  if (e < EE) {
    const int dst = ei[EE + e];
    const int pos = atomicAdd(&cursor[dst], 1);
    srcs[pos] = ei[e];
  }
}

// h = relu(y2*scale+shift) (scale/shift from stats slot); write h;
// r = h @ linW + linb; segment-max via LDS staging (batch sorted).
__global__ __launch_bounds__(256) void bnrelu_readout_kernel(
    const float* __restrict__ y2, const float* __restrict__ stats_in,
    const float* __restrict__ gamma, const float* __restrict__ beta,
    float* __restrict__ hout, const float* __restrict__ linW,
    const float* __restrict__ linb, const int* __restrict__ batch,
    unsigned* __restrict__ outmax) {
  __shared__ float Wl[HH * 9];
  __shared__ float lb[8];
  __shared__ float ssl[128];
  __shared__ unsigned smax[8][8];
  const int t = threadIdx.x;
  if (t < 64) {
#pragma unroll
    for (int j = 0; j < 8; ++j) Wl[t * 9 + j] = linW[t * 8 + j];
    const float inv = 1.f / (float)NN;
    const float mean = stats_in[t] * inv;
    const float var = stats_in[64 + t] * inv - mean * mean;
    const float sc = gamma[t] * rsqrtf(var + BN_EPS);
    ssl[t] = sc;
    ssl[64 + t] = fmaf(-mean, sc, beta[t]);
  }
  if (t < 8) lb[t] = linb[t];
  if (t >= 64 && t < 128) smax[(t - 64) >> 3][(t - 64) & 7] = 0u;
  const int gfirst = batch[blockIdx.x * RNODES < NN ? blockIdx.x * RNODES : NN - 1];
  __syncthreads();
  const int nl = t >> 3;
  const int c0 = (t & 7) * 8;
  const int b0 = t & 1, b1 = (t >> 1) & 1, b2 = (t >> 2) & 1;
#pragma unroll
  for (int chunk = 0; chunk < RNODES / 32; ++chunk) {
    const int n = blockIdx.x * RNODES + chunk * 32 + nl;
    if (n < NN) {
      float hv[8];
      {
        const float4 v0 = *(const float4*)&y2[n * HH + c0];
        const float4 v1 = *(const float4*)&y2[n * HH + c0 + 4];
        hv[0] = fmaxf(fmaf(v0.x, ssl[c0 + 0], ssl[64 + c0 + 0]), 0.f);
        hv[1] = fmaxf(fmaf(v0.y, ssl[c0 + 1], ssl[64 + c0 + 1]), 0.f);
        hv[2] = fmaxf(fmaf(v0.z, ssl[c0 + 2], ssl[64 + c0 + 2]), 0.f);
        hv[3] = fmaxf(fmaf(v0.w, ssl[c0 + 3], ssl[64 + c0 + 3]), 0.f);
        hv[4] = fmaxf(fmaf(v1.x, ssl[c0 + 4], ssl[64 + c0 + 4]), 0.f);
        hv[5] = fmaxf(fmaf(v1.y, ssl[c0 + 5], ssl[64 + c0 + 5]), 0.f);
        hv[6] = fmaxf(fmaf(v1.z, ssl[c0 + 6], ssl[64 + c0 + 6]), 0.f);
        hv[7] = fmaxf(fmaf(v1.w, ssl[c0 + 7], ssl[64 + c0 + 7]), 0.f);
      }
      *(float4*)&hout[n * HH + c0] = make_float4(hv[0], hv[1], hv[2], hv[3]);
      *(float4*)&hout[n * HH + c0 + 4] = make_float4(hv[4], hv[5], hv[6], hv[7]);
      float rr[8] = {0, 0, 0, 0, 0, 0, 0, 0};
#pragma unroll
      for (int j = 0; j < 8; ++j) {
        const float a = hv[j];
        const int k = c0 + j;
#pragma unroll
        for (int u = 0; u < 8; ++u) rr[u] = fmaf(a, Wl[k * 9 + u], rr[u]);
      }
      // reduce-scatter butterfly: lane (t&7) ends with full sum for u == t&7
      float s4[4];
#pragma unroll
      for (int i = 0; i < 4; ++i) {
        const float keepv = b0 ? rr[2 * i + 1] : rr[2 * i];
        const float send = b0 ? rr[2 * i] : rr[2 * i + 1];
        s4[i] = keepv + __shfl_xor(send, 1);
      }
      float s2[2];
#pragma unroll
      for (int i = 0; i < 2; ++i) {
        const float keepv = b1 ? s4[2 * i + 1] : s4[2 * i];
        const float send = b1 ? s4[2 * i] : s4[2 * i + 1];
        s2[i] = keepv + __shfl_xor(send, 2);
      }
      const float keepv = b2 ? s2[1] : s2[0];
      const float send = b2 ? s2[0] : s2[1];
      const float v = keepv + __shfl_xor(send, 4) + lb[t & 7];
      const int g = batch[n];
      const int gidx = g - gfirst;
      const unsigned ev = enc_f32(v);
      if (gidx < 8)
        atomicMax(&smax[gidx][t & 7], ev);
      else
        atomicMax(&outmax[g * 8 + (t & 7)], ev);
    }
  }
  __syncthreads();
  if (t < 64) {
    const unsigned vv = smax[t >> 3][t & 7];
    if (vv) atomicMax(&outmax[(gfirst + (t >> 3)) * 8 + (t & 7)], vv);
  }
}

__global__ void combine_kernel(const unsigned* __restrict__ outmax,
                               float* __restrict__ out) {
  const int i = blockIdx.x * 64 + threadIdx.x;  // 8 x 64 = 512
  float s = 0.f;
#pragma unroll
  for (int l = 0; l < 4; ++l) s += dec_f32(outmax[l * GG * TT + i]);
  out[i] = s;
}

extern "C" void kernel_launch(void* const* d_in, const int* in_sizes, int n_in,
                              void* d_out, int out_size, void* d_ws,
                              size_t ws_size, hipStream_t stream) {
  const float* x      = (const float*)d_in[0];
  const int*   ei     = (const int*)d_in[1];
  const int*   batch  = (const int*)d_in[2];
  const float* fh_W1  = (const float*)d_in[3];
  const float* fh_b1  = (const float*)d_in[4];
  const float* fh_g1  = (const float*)d_in[5];
  const float* fh_be1 = (const float*)d_in[6];
  const float* fh_W2  = (const float*)d_in[7];
  const float* fh_b2  = (const float*)d_in[8];
  const float* fh_g2  = (const float*)d_in[9];
  const float* fh_be2 = (const float*)d_in[10];
  const float* cv_W1  = (const float*)d_in[11];
  const float* cv_b1  = (const float*)d_in[12];
  const float* cv_g1  = (const float*)d_in[13];
  const float* cv_be1 = (const float*)d_in[14];
  const float* cv_W2  = (const float*)d_in[15];
  const float* cv_b2  = (const float*)d_in[16];
  const float* cv_g2  = (const float*)d_in[17];
  const float* cv_be2 = (const float*)d_in[18];
  const float* lin_W  = (const float*)d_in[19];
  const float* lin_b  = (const float*)d_in[20];

  float* out = (float*)d_out;  // [64,8]
  float* h = out + GG * TT;    // [N,64] final h lives in d_out; running h buf.

  char* w = (char*)d_ws;
  float* stats = (float*)w;                       w += 8 * 128 * 4;   // 8 slots
  unsigned* outmax = (unsigned*)w;                w += 4 * GG * TT * 4;
  int* bsum = (int*)w;                            w += 256 * 4;
  int* offs = (int*)w;                            w += (NN + 1) * 4;
  int* srcs = (int*)w;                            w += (size_t)EE * 4;
  w = (char*)(((size_t)w + 15) & ~(size_t)15);
  float* y1 = (float*)w;                          w += (size_t)NN * HH * 4;
  float* y2 = (float*)w;                          w += (size_t)NN * HH * 4;
  int* deg = (int*)y1;         // build-time aliases (dead before y1 written)
  int* cursor = ((int*)y1) + NN;

  const int NBLK = (NN + 63) / 64;        // 782
  const int NRD = (NN + RNODES - 1) / RNODES;  // 391

  // stats (4KB) and outmax (8KB) are contiguous: one memset
  hipMemsetAsync(stats, 0, (8 * 128 + 4 * GG * TT) * sizeof(float), stream);

  // ---- CSR build ----
  hipMemsetAsync(deg, 0, NN * sizeof(int), stream);
  hist_kernel<<<(EE + 255) / 256, 256, 0, stream>>>(ei, deg);
  scan1_kernel<<<NB_SCAN, 256, 0, stream>>>(deg, bsum);
  scan2_kernel<<<1, 256, 0, stream>>>(bsum);
  scan3_kernel<<<NB_SCAN, 256, 0, stream>>>(deg, bsum, offs, cursor);
  fill_kernel<<<(EE + 255) / 256, 256, 0, stream>>>(ei, cursor, srcs);

  // ---- first_h ----
  mm_stats_kernel<FIN, 0><<<NBLK, 256, 0, stream>>>(
      x, nullptr, nullptr, nullptr, nullptr, nullptr, fh_W1, fh_b1, y1, stats);
  mm_stats_kernel<HH, 1><<<NBLK, 256, 0, stream>>>(
      y1, nullptr, nullptr, stats, fh_g1, fh_be1, fh_W2, fh_b2, y2, stats + 128);
  bnrelu_readout_kernel<<<NRD, 256, 0, stream>>>(
      y2, stats + 128, fh_g2, fh_be2, h, lin_W, lin_b, batch, outmax);

  // ---- GIN conv layers ----
  for (int l = 0; l < NCONVS; ++l) {
    float* s1 = stats + (2 + 2 * l) * 128;
    float* s2 = stats + (3 + 2 * l) * 128;
    mm_stats_kernel<HH, 2><<<NBLK, 256, 0, stream>>>(
        h, offs, srcs, nullptr, nullptr, nullptr,
        cv_W1 + l * HH * HH, cv_b1 + l * HH, y1, s1);
    mm_stats_kernel<HH, 1><<<NBLK, 256, 0, stream>>>(
        y1, nullptr, nullptr, s1, cv_g1 + l * HH, cv_be1 + l * HH,
        cv_W2 + l * HH * HH, cv_b2 + l * HH, y2, s2);
    bnrelu_readout_kernel<<<NRD, 256, 0, stream>>>(
        y2, s2, cv_g2 + l * HH, cv_be2 + l * HH, h,
        lin_W + (l + 1) * HH * TT, lin_b + (l + 1) * TT, batch,
        outmax + (l + 1) * GG * TT);
  }
  combine_kernel<<<8, 64, 0, stream>>>(outmax, out);
}

// Round 5
// 459.518 us; speedup vs baseline: 1.0450x; 1.0450x over previous
//
#include <hip/hip_runtime.h>
#include <hip/hip_fp16.h>

#define NN 50000
#define EE 800000
#define FIN 128
#define HH 64
#define TT 8
#define GG 64
#define NCONVS 3
#define BN_EPS 1e-5f
#define NB_SCAN 196   // ceil(NN/256)
#define RNODES 128    // nodes per readout block

__device__ __forceinline__ unsigned enc_f32(float x) {
  unsigned u = __float_as_uint(x);
  return (u & 0x80000000u) ? ~u : (u | 0x80000000u);
}
__device__ __forceinline__ float dec_f32(unsigned e) {
  unsigned u = (e & 0x80000000u) ? (e & 0x7fffffffu) : ~e;
  return __uint_as_float(u);
}

// y[N,64] = op(...) @ W[K,64] + bias, with fused per-column BN stats of y.
// MODE 0: in = raw fp32 (K=FIN)
// MODE 1: relu(in*scale+shift), scale/shift from stats_in+gamma/beta
// MODE 2: h16[row] + agg[row]  (GIN: (1+eps)*h + agg, eps=0; h in fp16)
// Each block processes 64 rows (4 chunks of 16); flushes stats once.
template <int K, int MODE>
__global__ __launch_bounds__(256) void mm_stats_kernel(
    const float* __restrict__ in, const __half* __restrict__ hin,
    const float* __restrict__ agg, const float* __restrict__ stats_in,
    const float* __restrict__ gamma, const float* __restrict__ beta,
    const float* __restrict__ W, const float* __restrict__ bias,
    float* __restrict__ y, float* __restrict__ stats_out) {
  __shared__ float Wl[K * HH];
  __shared__ float Al[16][K + 1];
  __shared__ float ssl[128];
  __shared__ float sred[4][128];
  const int t = threadIdx.x;
  {
    const float4* W4 = (const float4*)W;
    float4* Wl4 = (float4*)Wl;
#pragma unroll
    for (int i = 0; i < (K * HH) / 1024; ++i) Wl4[t + i * 256] = W4[t + i * 256];
  }
  if (MODE == 1 && t < 64) {
    const float inv = 1.f / (float)NN;
    const float mean = stats_in[t] * inv;
    const float var = stats_in[64 + t] * inv - mean * mean;
    const float sc = gamma[t] * rsqrtf(var + BN_EPS);
    ssl[t] = sc;
    ssl[64 + t] = fmaf(-mean, sc, beta[t]);
  }
  const int r = t >> 4, g = t & 15;
  const float4 bb = *(const float4*)&bias[g * 4];
  float st_s[4] = {0.f, 0.f, 0.f, 0.f}, st_q[4] = {0.f, 0.f, 0.f, 0.f};
  __syncthreads();

#pragma unroll
  for (int chunk = 0; chunk < 4; ++chunk) {
    const int row = blockIdx.x * 64 + chunk * 16 + r;
    if (row < NN) {
      if (MODE == 0) {
#pragma unroll
        for (int p = 0; p < K / 64; ++p) {
          const int c0 = g * 4 + p * 64;
          const float4 v = *(const float4*)&in[row * K + c0];
          Al[r][c0 + 0] = v.x; Al[r][c0 + 1] = v.y;
          Al[r][c0 + 2] = v.z; Al[r][c0 + 3] = v.w;
        }
      } else if (MODE == 1) {
        const int c0 = g * 4;
        const float4 v = *(const float4*)&in[row * HH + c0];
        Al[r][c0 + 0] = fmaxf(fmaf(v.x, ssl[c0 + 0], ssl[64 + c0 + 0]), 0.f);
        Al[r][c0 + 1] = fmaxf(fmaf(v.y, ssl[c0 + 1], ssl[64 + c0 + 1]), 0.f);
        Al[r][c0 + 2] = fmaxf(fmaf(v.z, ssl[c0 + 2], ssl[64 + c0 + 2]), 0.f);
        Al[r][c0 + 3] = fmaxf(fmaf(v.w, ssl[c0 + 3], ssl[64 + c0 + 3]), 0.f);
      } else {  // MODE 2
        const int c0 = g * 4;
        const int2 hraw = *(const int2*)&hin[row * HH + c0];
        const float2 f0 = __half22float2(*(const __half2*)&hraw.x);
        const float2 f1 = __half22float2(*(const __half2*)&hraw.y);
        const float4 a = *(const float4*)&agg[row * HH + c0];
        Al[r][c0 + 0] = f0.x + a.x; Al[r][c0 + 1] = f0.y + a.y;
        Al[r][c0 + 2] = f1.x + a.z; Al[r][c0 + 3] = f1.y + a.w;
      }
    } else {
#pragma unroll
      for (int p = 0; p < K / 64; ++p) {
        const int c0 = g * 4 + p * 64;
        Al[r][c0 + 0] = 0.f; Al[r][c0 + 1] = 0.f;
        Al[r][c0 + 2] = 0.f; Al[r][c0 + 3] = 0.f;
      }
    }
    __syncthreads();
    float ax = 0.f, ay = 0.f, az = 0.f, aw = 0.f;
#pragma unroll
    for (int k = 0; k < K; ++k) {
      const float a = Al[r][k];
      const float4 w = *(const float4*)&Wl[k * HH + g * 4];
      ax = fmaf(a, w.x, ax); ay = fmaf(a, w.y, ay);
      az = fmaf(a, w.z, az); aw = fmaf(a, w.w, aw);
    }
    if (row < NN) {
      float4 o;
      o.x = ax + bb.x; o.y = ay + bb.y; o.z = az + bb.z; o.w = aw + bb.w;
      *(float4*)&y[row * HH + g * 4] = o;
      st_s[0] += o.x; st_s[1] += o.y; st_s[2] += o.z; st_s[3] += o.w;
      st_q[0] = fmaf(o.x, o.x, st_q[0]); st_q[1] = fmaf(o.y, o.y, st_q[1]);
      st_q[2] = fmaf(o.z, o.z, st_q[2]); st_q[3] = fmaf(o.w, o.w, st_q[3]);
    }
    __syncthreads();
  }
#pragma unroll
  for (int off = 16; off <= 32; off <<= 1) {
#pragma unroll
    for (int i = 0; i < 4; ++i) {
      st_s[i] += __shfl_xor(st_s[i], off);
      st_q[i] += __shfl_xor(st_q[i], off);
    }
  }
  const int wave = t >> 6, lane = t & 63;
  if (lane < 16) {
#pragma unroll
    for (int i = 0; i < 4; ++i) {
      sred[wave][lane * 4 + i] = st_s[i];
      sred[wave][64 + lane * 4 + i] = st_q[i];
    }
  }
  __syncthreads();
  if (t < 128)
    atomicAdd(&stats_out[t],
              sred[0][t] + sred[1][t] + sred[2][t] + sred[3][t]);
}

// ---------------- CSR build ----------------
__global__ __launch_bounds__(256) void hist_kernel(const int* __restrict__ ei,
                                                   int* __restrict__ deg) {
  const int e = blockIdx.x * 256 + threadIdx.x;
  if (e < EE) atomicAdd(&deg[ei[EE + e]], 1);
}

__global__ __launch_bounds__(256) void scan1_kernel(const int* __restrict__ deg,
                                                    int* __restrict__ bsum) {
  __shared__ int s[256];
  const int i = blockIdx.x * 256 + threadIdx.x;
  s[threadIdx.x] = (i < NN) ? deg[i] : 0;
  __syncthreads();
  for (int off = 128; off > 0; off >>= 1) {
    if (threadIdx.x < off) s[threadIdx.x] += s[threadIdx.x + off];
    __syncthreads();
  }
  if (threadIdx.x == 0) bsum[blockIdx.x] = s[0];
}

__global__ void scan2_kernel(int* __restrict__ bsum) {
  __shared__ int s[256];
  const int t = threadIdx.x;
  const int orig = (t < NB_SCAN) ? bsum[t] : 0;
  s[t] = orig;
  __syncthreads();
  for (int off = 1; off < 256; off <<= 1) {
    const int u = (t >= off) ? s[t - off] : 0;
    __syncthreads();
    s[t] += u;
    __syncthreads();
  }
  if (t < NB_SCAN) bsum[t] = s[t] - orig;  // exclusive
}

__global__ __launch_bounds__(256) void scan3_kernel(const int* __restrict__ deg,
                                                    const int* __restrict__ bsum,
                                                    int* __restrict__ offs,
                                                    int* __restrict__ cursor) {
  __shared__ int s[256];
  const int t = threadIdx.x;
  const int i = blockIdx.x * 256 + t;
  const int orig = (i < NN) ? deg[i] : 0;
  s[t] = orig;
  __syncthreads();
  for (int off = 1; off < 256; off <<= 1) {
    const int u = (t >= off) ? s[t - off] : 0;
    __syncthreads();
    s[t] += u;
    __syncthreads();
  }
  const int excl = s[t] - orig + bsum[blockIdx.x];
  if (i < NN) {
    offs[i] = excl;
    cursor[i] = excl;
    if (i == NN - 1) offs[NN] = excl + orig;
  }
}

__global__ __launch_bounds__(256) void fill_kernel(const int* __restrict__ ei,
                                                   int* __restrict__ cursor,
                                                   int* __restrict__ srcs) {
  const int e = blockIdx.x * 256 + threadIdx.x;
  if (e < EE) {
    const int dst = ei[EE + e];
    const int pos = atomicAdd(&cursor[dst], 1);
    srcs[pos] = ei[e];
  }
}

__device__ __forceinline__ void acc_half8(const int4 r, float4& lo, float4& hi) {
  const __half2* p = (const __half2*)&r;
  const float2 f0 = __half22float2(p[0]);
  const float2 f1 = __half22float2(p[1]);
  const float2 f2 = __half22float2(p[2]);
  const float2 f3 = __half22float2(p[3]);
  lo.x += f0.x; lo.y += f0.y; lo.z += f1.x; lo.w += f1.y;
  hi.x += f2.x; hi.y += f2.y; hi.z += f3.x; hi.w += f3.y;
}

// agg[n] = sum over CSR neighbors of h16[src] (fp32 accumulate).
// 8 lanes per node, 8 cols each; 2-way unrolled.
__global__ __launch_bounds__(256) void gather16_kernel(
    const int* __restrict__ offs, const int* __restrict__ srcs,
    const __half* __restrict__ h16, float* __restrict__ agg) {
  const int gid = blockIdx.x * 256 + threadIdx.x;
  const int n = gid >> 3, lane = gid & 7;
  if (n >= NN) return;
  const int c0 = lane * 8;
  const int s0 = offs[n], s1 = offs[n + 1];
  float4 aA0 = make_float4(0, 0, 0, 0), aA1 = make_float4(0, 0, 0, 0);
  float4 aB0 = make_float4(0, 0, 0, 0), aB1 = make_float4(0, 0, 0, 0);
  int j = s0;
  for (; j + 1 < s1; j += 2) {
    const int sA = srcs[j], sB = srcs[j + 1];
    const int4 rA = *(const int4*)&h16[sA * HH + c0];
    const int4 rB = *(const int4*)&h16[sB * HH + c0];
    acc_half8(rA, aA0, aA1);
    acc_half8(rB, aB0, aB1);
  }
  if (j < s1) {
    const int4 rA = *(const int4*)&h16[srcs[j] * HH + c0];
    acc_half8(rA, aA0, aA1);
  }
  aA0.x += aB0.x; aA0.y += aB0.y; aA0.z += aB0.z; aA0.w += aB0.w;
  aA1.x += aB1.x; aA1.y += aB1.y; aA1.z += aB1.z; aA1.w += aB1.w;
  *(float4*)&agg[n * HH + c0] = aA0;
  *(float4*)&agg[n * HH + c0 + 4] = aA1;
}

// h = relu(y2*scale+shift) (scale/shift from stats slot);
// WMODE 0: write h16 (fp16, feeds next gather/conv). WMODE 1: write fp32 h.
// r = h @ linW + linb; segment-max via LDS staging (batch sorted).
template <int WMODE>
__global__ __launch_bounds__(256) void bnrelu_readout_kernel(
    const float* __restrict__ y2, const float* __restrict__ stats_in,
    const float* __restrict__ gamma, const float* __restrict__ beta,
    float* __restrict__ hout, __half* __restrict__ h16out,
    const float* __restrict__ linW, const float* __restrict__ linb,
    const int* __restrict__ batch, unsigned* __restrict__ outmax) {
  __shared__ float Wl[HH * 9];
  __shared__ float lb[8];
  __shared__ float ssl[128];
  __shared__ unsigned smax[8][8];
  const int t = threadIdx.x;
  if (t < 64) {
#pragma unroll
    for (int j = 0; j < 8; ++j) Wl[t * 9 + j] = linW[t * 8 + j];
    const float inv = 1.f / (float)NN;
    const float mean = stats_in[t] * inv;
    const float var = stats_in[64 + t] * inv - mean * mean;
    const float sc = gamma[t] * rsqrtf(var + BN_EPS);
    ssl[t] = sc;
    ssl[64 + t] = fmaf(-mean, sc, beta[t]);
  }
  if (t < 8) lb[t] = linb[t];
  if (t >= 64 && t < 128) smax[(t - 64) >> 3][(t - 64) & 7] = 0u;
  const int gfirst = batch[blockIdx.x * RNODES < NN ? blockIdx.x * RNODES : NN - 1];
  __syncthreads();
  const int nl = t >> 3;
  const int c0 = (t & 7) * 8;
  const int b0 = t & 1, b1 = (t >> 1) & 1, b2 = (t >> 2) & 1;
#pragma unroll
  for (int chunk = 0; chunk < RNODES / 32; ++chunk) {
    const int n = blockIdx.x * RNODES + chunk * 32 + nl;
    if (n < NN) {
      float hv[8];
      {
        const float4 v0 = *(const float4*)&y2[n * HH + c0];
        const float4 v1 = *(const float4*)&y2[n * HH + c0 + 4];
        hv[0] = fmaxf(fmaf(v0.x, ssl[c0 + 0], ssl[64 + c0 + 0]), 0.f);
        hv[1] = fmaxf(fmaf(v0.y, ssl[c0 + 1], ssl[64 + c0 + 1]), 0.f);
        hv[2] = fmaxf(fmaf(v0.z, ssl[c0 + 2], ssl[64 + c0 + 2]), 0.f);
        hv[3] = fmaxf(fmaf(v0.w, ssl[c0 + 3], ssl[64 + c0 + 3]), 0.f);
        hv[4] = fmaxf(fmaf(v1.x, ssl[c0 + 4], ssl[64 + c0 + 4]), 0.f);
        hv[5] = fmaxf(fmaf(v1.y, ssl[c0 + 5], ssl[64 + c0 + 5]), 0.f);
        hv[6] = fmaxf(fmaf(v1.z, ssl[c0 + 6], ssl[64 + c0 + 6]), 0.f);
        hv[7] = fmaxf(fmaf(v1.w, ssl[c0 + 7], ssl[64 + c0 + 7]), 0.f);
      }
      if (WMODE == 1) {
        *(float4*)&hout[n * HH + c0] = make_float4(hv[0], hv[1], hv[2], hv[3]);
        *(float4*)&hout[n * HH + c0 + 4] = make_float4(hv[4], hv[5], hv[6], hv[7]);
      } else {
        const __half2 p0 = __floats2half2_rn(hv[0], hv[1]);
        const __half2 p1 = __floats2half2_rn(hv[2], hv[3]);
        const __half2 p2 = __floats2half2_rn(hv[4], hv[5]);
        const __half2 p3 = __floats2half2_rn(hv[6], hv[7]);
        int4 pk;
        pk.x = *(const int*)&p0; pk.y = *(const int*)&p1;
        pk.z = *(const int*)&p2; pk.w = *(const int*)&p3;
        *(int4*)&h16out[n * HH + c0] = pk;
      }
      float rr[8] = {0, 0, 0, 0, 0, 0, 0, 0};
#pragma unroll
      for (int j = 0; j < 8; ++j) {
        const float a = hv[j];
        const int k = c0 + j;
#pragma unroll
        for (int u = 0; u < 8; ++u) rr[u] = fmaf(a, Wl[k * 9 + u], rr[u]);
      }
      // reduce-scatter butterfly: lane (t&7) ends with full sum for u == t&7
      float s4[4];
#pragma unroll
      for (int i = 0; i < 4; ++i) {
        const float keepv = b0 ? rr[2 * i + 1] : rr[2 * i];
        const float send = b0 ? rr[2 * i] : rr[2 * i + 1];
        s4[i] = keepv + __shfl_xor(send, 1);
      }
      float s2[2];
#pragma unroll
      for (int i = 0; i < 2; ++i) {
        const float keepv = b1 ? s4[2 * i + 1] : s4[2 * i];
        const float send = b1 ? s4[2 * i] : s4[2 * i + 1];
        s2[i] = keepv + __shfl_xor(send, 2);
      }
      const float keepv = b2 ? s2[1] : s2[0];
      const float send = b2 ? s2[0] : s2[1];
      const float v = keepv + __shfl_xor(send, 4) + lb[t & 7];
      const int g = batch[n];
      const int gidx = g - gfirst;
      const unsigned ev = enc_f32(v);
      if (gidx < 8)
        atomicMax(&smax[gidx][t & 7], ev);
      else
        atomicMax(&outmax[g * 8 + (t & 7)], ev);
    }
  }
  __syncthreads();
  if (t < 64) {
    const unsigned vv = smax[t >> 3][t & 7];
    if (vv) atomicMax(&outmax[(gfirst + (t >> 3)) * 8 + (t & 7)], vv);
  }
}

__global__ void combine_kernel(const unsigned* __restrict__ outmax,
                               float* __restrict__ out) {
  const int i = blockIdx.x * 64 + threadIdx.x;  // 8 x 64 = 512
  float s = 0.f;
#pragma unroll
  for (int l = 0; l < 4; ++l) s += dec_f32(outmax[l * GG * TT + i]);
  out[i] = s;
}

extern "C" void kernel_launch(void* const* d_in, const int* in_sizes, int n_in,
                              void* d_out, int out_size, void* d_ws,
                              size_t ws_size, hipStream_t stream) {
  const float* x      = (const float*)d_in[0];
  const int*   ei     = (const int*)d_in[1];
  const int*   batch  = (const int*)d_in[2];
  const float* fh_W1  = (const float*)d_in[3];
  const float* fh_b1  = (const float*)d_in[4];
  const float* fh_g1  = (const float*)d_in[5];
  const float* fh_be1 = (const float*)d_in[6];
  const float* fh_W2  = (const float*)d_in[7];
  const float* fh_b2  = (const float*)d_in[8];
  const float* fh_g2  = (const float*)d_in[9];
  const float* fh_be2 = (const float*)d_in[10];
  const float* cv_W1  = (const float*)d_in[11];
  const float* cv_b1  = (const float*)d_in[12];
  const float* cv_g1  = (const float*)d_in[13];
  const float* cv_be1 = (const float*)d_in[14];
  const float* cv_W2  = (const float*)d_in[15];
  const float* cv_b2  = (const float*)d_in[16];
  const float* cv_g2  = (const float*)d_in[17];
  const float* cv_be2 = (const float*)d_in[18];
  const float* lin_W  = (const float*)d_in[19];
  const float* lin_b  = (const float*)d_in[20];

  float* out = (float*)d_out;  // [64,8]
  float* h = out + GG * TT;    // [N,64] fp32 final h (written by last readout)

  char* w = (char*)d_ws;
  float* stats = (float*)w;                       w += 8 * 128 * 4;   // 8 slots
  unsigned* outmax = (unsigned*)w;                w += 4 * GG * TT * 4;
  int* bsum = (int*)w;                            w += 256 * 4;
  int* offs = (int*)w;                            w += (NN + 1) * 4;
  int* srcs = (int*)w;                            w += (size_t)EE * 4;
  w = (char*)(((size_t)w + 15) & ~(size_t)15);
  __half* h16 = (__half*)w;                       w += (size_t)NN * HH * 2;
  w = (char*)(((size_t)w + 15) & ~(size_t)15);
  float* y1 = (float*)w;                          w += (size_t)NN * HH * 4;
  float* y2 = (float*)w;                          w += (size_t)NN * HH * 4;
  float* agg = y2;             // aliased: agg dead before y2 written
  int* deg = (int*)y1;         // build-time aliases (dead before y1 written)
  int* cursor = ((int*)y1) + NN;

  const int NBLK = (NN + 63) / 64;             // 782
  const int NRD = (NN + RNODES - 1) / RNODES;  // 391
  const int NGA = (NN * 8 + 255) / 256;        // 1563

  hipMemsetAsync(stats, 0, (8 * 128 + 4 * GG * TT) * sizeof(float), stream);

  // ---- CSR build ----
  hipMemsetAsync(deg, 0, NN * sizeof(int), stream);
  hist_kernel<<<(EE + 255) / 256, 256, 0, stream>>>(ei, deg);
  scan1_kernel<<<NB_SCAN, 256, 0, stream>>>(deg, bsum);
  scan2_kernel<<<1, 256, 0, stream>>>(bsum);
  scan3_kernel<<<NB_SCAN, 256, 0, stream>>>(deg, bsum, offs, cursor);
  fill_kernel<<<(EE + 255) / 256, 256, 0, stream>>>(ei, cursor, srcs);

  // ---- first_h ----
  mm_stats_kernel<FIN, 0><<<NBLK, 256, 0, stream>>>(
      x, nullptr, nullptr, nullptr, nullptr, nullptr, fh_W1, fh_b1, y1, stats);
  mm_stats_kernel<HH, 1><<<NBLK, 256, 0, stream>>>(
      y1, nullptr, nullptr, stats, fh_g1, fh_be1, fh_W2, fh_b2, y2, stats + 128);
  bnrelu_readout_kernel<0><<<NRD, 256, 0, stream>>>(
      y2, stats + 128, fh_g2, fh_be2, h, h16, lin_W, lin_b, batch, outmax);

  // ---- GIN conv layers ----
  for (int l = 0; l < NCONVS; ++l) {
    float* s1 = stats + (2 + 2 * l) * 128;
    float* s2 = stats + (3 + 2 * l) * 128;
    gather16_kernel<<<NGA, 256, 0, stream>>>(offs, srcs, h16, agg);
    mm_stats_kernel<HH, 2><<<NBLK, 256, 0, stream>>>(
        nullptr, h16, agg, nullptr, nullptr, nullptr,
        cv_W1 + l * HH * HH, cv_b1 + l * HH, y1, s1);
    mm_stats_kernel<HH, 1><<<NBLK, 256, 0, stream>>>(
        y1, nullptr, nullptr, s1, cv_g1 + l * HH, cv_be1 + l * HH,
        cv_W2 + l * HH * HH, cv_b2 + l * HH, y2, s2);
    if (l == NCONVS - 1) {
      bnrelu_readout_kernel<1><<<NRD, 256, 0, stream>>>(
          y2, s2, cv_g2 + l * HH, cv_be2 + l * HH, h, h16,
          lin_W + (l + 1) * HH * TT, lin_b + (l + 1) * TT, batch,
          outmax + (l + 1) * GG * TT);
    } else {
      bnrelu_readout_kernel<0><<<NRD, 256, 0, stream>>>(
          y2, s2, cv_g2 + l * HH, cv_be2 + l * HH, h, h16,
          lin_W + (l + 1) * HH * TT, lin_b + (l + 1) * TT, batch,
          outmax + (l + 1) * GG * TT);
    }
  }
  combine_kernel<<<8, 64, 0, stream>>>(outmax, out);
}

// Round 6
// 407.082 us; speedup vs baseline: 1.1796x; 1.1288x over previous
//
#include <hip/hip_runtime.h>
#include <hip/hip_fp16.h>

#define NN 50000
#define EE 800000
#define FIN 128
#define HH 64
#define TT 8
#define GG 64
#define NCONVS 3
#define BN_EPS 1e-5f
#define RNODES 128            // nodes per readout block
#define NBKT 196              // ceil(NN/256) buckets of 256 nodes
#define SCAT_CHUNK 2048       // edges per bscatter block

__device__ __forceinline__ unsigned enc_f32(float x) {
  unsigned u = __float_as_uint(x);
  return (u & 0x80000000u) ? ~u : (u | 0x80000000u);
}
__device__ __forceinline__ float dec_f32(unsigned e) {
  unsigned u = (e & 0x80000000u) ? (e & 0x7fffffffu) : ~e;
  return __uint_as_float(u);
}

// y16[N,64] = op(...) @ W[K,64] + bias (output fp16), fused BN stats (fp32).
// MODE 0: in = raw fp32 (K=FIN)
// MODE 1: relu(hin*scale+shift), hin fp16, scale/shift from stats_in
// MODE 2: hin[row] (fp16 h) + agg[row] (fp32)
template <int K, int MODE>
__global__ __launch_bounds__(256) void mm_stats_kernel(
    const float* __restrict__ in, const __half* __restrict__ hin,
    const float* __restrict__ agg, const float* __restrict__ stats_in,
    const float* __restrict__ gamma, const float* __restrict__ beta,
    const float* __restrict__ W, const float* __restrict__ bias,
    __half* __restrict__ y16, float* __restrict__ stats_out) {
  __shared__ float Wl[K * HH];
  __shared__ float Al[16][K + 1];
  __shared__ float ssl[128];
  __shared__ float sred[4][128];
  const int t = threadIdx.x;
  {
    const float4* W4 = (const float4*)W;
    float4* Wl4 = (float4*)Wl;
#pragma unroll
    for (int i = 0; i < (K * HH) / 1024; ++i) Wl4[t + i * 256] = W4[t + i * 256];
  }
  if (MODE == 1 && t < 64) {
    const float inv = 1.f / (float)NN;
    const float mean = stats_in[t] * inv;
    const float var = stats_in[64 + t] * inv - mean * mean;
    const float sc = gamma[t] * rsqrtf(var + BN_EPS);
    ssl[t] = sc;
    ssl[64 + t] = fmaf(-mean, sc, beta[t]);
  }
  const int r = t >> 4, g = t & 15;
  const float4 bb = *(const float4*)&bias[g * 4];
  float st_s[4] = {0.f, 0.f, 0.f, 0.f}, st_q[4] = {0.f, 0.f, 0.f, 0.f};
  __syncthreads();

#pragma unroll
  for (int chunk = 0; chunk < 4; ++chunk) {
    const int row = blockIdx.x * 64 + chunk * 16 + r;
    if (row < NN) {
      if (MODE == 0) {
#pragma unroll
        for (int p = 0; p < K / 64; ++p) {
          const int c0 = g * 4 + p * 64;
          const float4 v = *(const float4*)&in[row * K + c0];
          Al[r][c0 + 0] = v.x; Al[r][c0 + 1] = v.y;
          Al[r][c0 + 2] = v.z; Al[r][c0 + 3] = v.w;
        }
      } else if (MODE == 1) {
        const int c0 = g * 4;
        const int2 hraw = *(const int2*)&hin[row * HH + c0];
        const float2 f0 = __half22float2(*(const __half2*)&hraw.x);
        const float2 f1 = __half22float2(*(const __half2*)&hraw.y);
        Al[r][c0 + 0] = fmaxf(fmaf(f0.x, ssl[c0 + 0], ssl[64 + c0 + 0]), 0.f);
        Al[r][c0 + 1] = fmaxf(fmaf(f0.y, ssl[c0 + 1], ssl[64 + c0 + 1]), 0.f);
        Al[r][c0 + 2] = fmaxf(fmaf(f1.x, ssl[c0 + 2], ssl[64 + c0 + 2]), 0.f);
        Al[r][c0 + 3] = fmaxf(fmaf(f1.y, ssl[c0 + 3], ssl[64 + c0 + 3]), 0.f);
      } else {  // MODE 2
        const int c0 = g * 4;
        const int2 hraw = *(const int2*)&hin[row * HH + c0];
        const float2 f0 = __half22float2(*(const __half2*)&hraw.x);
        const float2 f1 = __half22float2(*(const __half2*)&hraw.y);
        const float4 a = *(const float4*)&agg[row * HH + c0];
        Al[r][c0 + 0] = f0.x + a.x; Al[r][c0 + 1] = f0.y + a.y;
        Al[r][c0 + 2] = f1.x + a.z; Al[r][c0 + 3] = f1.y + a.w;
      }
    } else {
#pragma unroll
      for (int p = 0; p < K / 64; ++p) {
        const int c0 = g * 4 + p * 64;
        Al[r][c0 + 0] = 0.f; Al[r][c0 + 1] = 0.f;
        Al[r][c0 + 2] = 0.f; Al[r][c0 + 3] = 0.f;
      }
    }
    __syncthreads();
    float ax = 0.f, ay = 0.f, az = 0.f, aw = 0.f;
#pragma unroll
    for (int k = 0; k < K; ++k) {
      const float a = Al[r][k];
      const float4 w = *(const float4*)&Wl[k * HH + g * 4];
      ax = fmaf(a, w.x, ax); ay = fmaf(a, w.y, ay);
      az = fmaf(a, w.z, az); aw = fmaf(a, w.w, aw);
    }
    if (row < NN) {
      float4 o;
      o.x = ax + bb.x; o.y = ay + bb.y; o.z = az + bb.z; o.w = aw + bb.w;
      const __half2 p0 = __floats2half2_rn(o.x, o.y);
      const __half2 p1 = __floats2half2_rn(o.z, o.w);
      int2 pk;
      pk.x = *(const int*)&p0; pk.y = *(const int*)&p1;
      *(int2*)&y16[row * HH + g * 4] = pk;
      st_s[0] += o.x; st_s[1] += o.y; st_s[2] += o.z; st_s[3] += o.w;
      st_q[0] = fmaf(o.x, o.x, st_q[0]); st_q[1] = fmaf(o.y, o.y, st_q[1]);
      st_q[2] = fmaf(o.z, o.z, st_q[2]); st_q[3] = fmaf(o.w, o.w, st_q[3]);
    }
    __syncthreads();
  }
#pragma unroll
  for (int off = 16; off <= 32; off <<= 1) {
#pragma unroll
    for (int i = 0; i < 4; ++i) {
      st_s[i] += __shfl_xor(st_s[i], off);
      st_q[i] += __shfl_xor(st_q[i], off);
    }
  }
  const int wave = t >> 6, lane = t & 63;
  if (lane < 16) {
#pragma unroll
    for (int i = 0; i < 4; ++i) {
      sred[wave][lane * 4 + i] = st_s[i];
      sred[wave][64 + lane * 4 + i] = st_q[i];
    }
  }
  __syncthreads();
  if (t < 128)
    atomicAdd(&stats_out[t],
              sred[0][t] + sred[1][t] + sred[2][t] + sred[3][t]);
}

// ---------------- bucketed CSR build ----------------
// K1: per-bucket edge counts (bucket = dst>>8), LDS-staged
__global__ __launch_bounds__(256) void bcount_kernel(const int* __restrict__ ei,
                                                     int* __restrict__ bcnt) {
  __shared__ int l[256];
  const int t = threadIdx.x;
  l[t] = 0;
  __syncthreads();
  for (int e = blockIdx.x * 256 + t; e < EE; e += gridDim.x * 256)
    atomicAdd(&l[ei[EE + e] >> 8], 1);
  __syncthreads();
  if (t < NBKT && l[t]) atomicAdd(&bcnt[t], l[t]);
}

// K2: single-block exclusive scan of bucket counts -> bbase, init bcur
__global__ void bscan_kernel(const int* __restrict__ bcnt,
                             int* __restrict__ bbase, int* __restrict__ bcur) {
  __shared__ int s[256];
  const int t = threadIdx.x;
  const int v = (t < NBKT) ? bcnt[t] : 0;
  s[t] = v;
  __syncthreads();
  for (int off = 1; off < 256; off <<= 1) {
    const int u = (t >= off) ? s[t - off] : 0;
    __syncthreads();
    s[t] += u;
    __syncthreads();
  }
  const int excl = s[t] - v;
  if (t < NBKT) {
    bbase[t] = excl;
    bcur[t] = excl;
  }
  if (t == 255) bbase[NBKT] = s[255];  // == EE
}

// K3: scatter packed (src, dstLocal) into bucket-contiguous ebuf.
// Block-aggregated cursors: one global atomic per touched bucket per block.
__global__ __launch_bounds__(256) void bscatter_kernel(
    const int* __restrict__ ei, int* __restrict__ bcur,
    unsigned long long* __restrict__ ebuf) {
  __shared__ int lcnt[256];
  __shared__ int lbase[256];
  const int t = threadIdx.x;
  lcnt[t] = 0;
  __syncthreads();
  const int e0 = blockIdx.x * SCAT_CHUNK;
  int mysrc[8], mydl[8], mybkt[8], myloc[8];
#pragma unroll
  for (int i = 0; i < 8; ++i) {
    const int e = e0 + i * 256 + t;
    if (e < EE) {
      const int dst = ei[EE + e];
      mybkt[i] = dst >> 8;
      mydl[i] = dst & 255;
      mysrc[i] = ei[e];
      myloc[i] = atomicAdd(&lcnt[mybkt[i]], 1);
    } else {
      mybkt[i] = -1;
    }
  }
  __syncthreads();
  if (t < NBKT && lcnt[t]) lbase[t] = atomicAdd(&bcur[t], lcnt[t]);
  __syncthreads();
#pragma unroll
  for (int i = 0; i < 8; ++i) {
    if (mybkt[i] >= 0) {
      const int pos = lbase[mybkt[i]] + myloc[i];
      ebuf[pos] = ((unsigned long long)(unsigned)mydl[i] << 32) |
                  (unsigned)mysrc[i];
    }
  }
}

// K4: one block per bucket: per-node degree (LDS), local scan -> offs,
// then place srcs within the bucket's contiguous CSR region.
__global__ __launch_bounds__(256) void bcsr_kernel(
    const int* __restrict__ bbase, const unsigned long long* __restrict__ ebuf,
    int* __restrict__ offs, int* __restrict__ srcs) {
  __shared__ int ldeg[256];
  __shared__ int sscan[256];
  __shared__ int lcur[256];
  const int t = threadIdx.x;
  const int b = blockIdx.x;
  const int e0 = bbase[b], e1 = bbase[b + 1];
  ldeg[t] = 0;
  __syncthreads();
  for (int e = e0 + t; e < e1; e += 256)
    atomicAdd(&ldeg[(int)(ebuf[e] >> 32)], 1);
  __syncthreads();
  const int v = ldeg[t];
  sscan[t] = v;
  __syncthreads();
  for (int off = 1; off < 256; off <<= 1) {
    const int u = (t >= off) ? sscan[t - off] : 0;
    __syncthreads();
    sscan[t] += u;
    __syncthreads();
  }
  const int excl = sscan[t] - v;
  const int node = b * 256 + t;
  if (node < NN) offs[node] = e0 + excl;
  if (b == NBKT - 1 && t == 0) offs[NN] = EE;
  lcur[t] = e0 + excl;
  __syncthreads();
  for (int e = e0 + t; e < e1; e += 256) {
    const unsigned long long u = ebuf[e];
    const int dl = (int)(u >> 32);
    const int pos = atomicAdd(&lcur[dl], 1);
    srcs[pos] = (int)(u & 0xffffffffu);
  }
}

__device__ __forceinline__ void acc_half8(const int4 r, float4& lo, float4& hi) {
  const __half2* p = (const __half2*)&r;
  const float2 f0 = __half22float2(p[0]);
  const float2 f1 = __half22float2(p[1]);
  const float2 f2 = __half22float2(p[2]);
  const float2 f3 = __half22float2(p[3]);
  lo.x += f0.x; lo.y += f0.y; lo.z += f1.x; lo.w += f1.y;
  hi.x += f2.x; hi.y += f2.y; hi.z += f3.x; hi.w += f3.y;
}

// agg[n] = sum over CSR neighbors of h16[src] (fp32 accumulate).
__global__ __launch_bounds__(256) void gather16_kernel(
    const int* __restrict__ offs, const int* __restrict__ srcs,
    const __half* __restrict__ h16, float* __restrict__ agg) {
  const int gid = blockIdx.x * 256 + threadIdx.x;
  const int n = gid >> 3, lane = gid & 7;
  if (n >= NN) return;
  const int c0 = lane * 8;
  const int s0 = offs[n], s1 = offs[n + 1];
  float4 aA0 = make_float4(0, 0, 0, 0), aA1 = make_float4(0, 0, 0, 0);
  float4 aB0 = make_float4(0, 0, 0, 0), aB1 = make_float4(0, 0, 0, 0);
  int j = s0;
  for (; j + 1 < s1; j += 2) {
    const int sA = srcs[j], sB = srcs[j + 1];
    const int4 rA = *(const int4*)&h16[sA * HH + c0];
    const int4 rB = *(const int4*)&h16[sB * HH + c0];
    acc_half8(rA, aA0, aA1);
    acc_half8(rB, aB0, aB1);
  }
  if (j < s1) {
    const int4 rA = *(const int4*)&h16[srcs[j] * HH + c0];
    acc_half8(rA, aA0, aA1);
  }
  aA0.x += aB0.x; aA0.y += aB0.y; aA0.z += aB0.z; aA0.w += aB0.w;
  aA1.x += aB1.x; aA1.y += aB1.y; aA1.z += aB1.z; aA1.w += aB1.w;
  *(float4*)&agg[n * HH + c0] = aA0;
  *(float4*)&agg[n * HH + c0 + 4] = aA1;
}

// h = relu(y2*scale+shift); WMODE 0: write h16 fp16; WMODE 1: write fp32 h.
// r = h @ linW + linb; segment-max via LDS staging (batch sorted).
template <int WMODE>
__global__ __launch_bounds__(256) void bnrelu_readout_kernel(
    const __half* __restrict__ y2, const float* __restrict__ stats_in,
    const float* __restrict__ gamma, const float* __restrict__ beta,
    float* __restrict__ hout, __half* __restrict__ h16out,
    const float* __restrict__ linW, const float* __restrict__ linb,
    const int* __restrict__ batch, unsigned* __restrict__ outmax) {
  __shared__ float Wl[HH * 9];
  __shared__ float lb[8];
  __shared__ float ssl[128];
  __shared__ unsigned smax[8][8];
  const int t = threadIdx.x;
  if (t < 64) {
#pragma unroll
    for (int j = 0; j < 8; ++j) Wl[t * 9 + j] = linW[t * 8 + j];
    const float inv = 1.f / (float)NN;
    const float mean = stats_in[t] * inv;
    const float var = stats_in[64 + t] * inv - mean * mean;
    const float sc = gamma[t] * rsqrtf(var + BN_EPS);
    ssl[t] = sc;
    ssl[64 + t] = fmaf(-mean, sc, beta[t]);
  }
  if (t < 8) lb[t] = linb[t];
  if (t >= 64 && t < 128) smax[(t - 64) >> 3][(t - 64) & 7] = 0u;
  const int gfirst = batch[blockIdx.x * RNODES < NN ? blockIdx.x * RNODES : NN - 1];
  __syncthreads();
  const int nl = t >> 3;
  const int c0 = (t & 7) * 8;
  const int b0 = t & 1, b1 = (t >> 1) & 1, b2 = (t >> 2) & 1;
#pragma unroll
  for (int chunk = 0; chunk < RNODES / 32; ++chunk) {
    const int n = blockIdx.x * RNODES + chunk * 32 + nl;
    if (n < NN) {
      float hv[8];
      {
        const int4 rv = *(const int4*)&y2[n * HH + c0];
        const __half2* hp = (const __half2*)&rv;
        const float2 f0 = __half22float2(hp[0]);
        const float2 f1 = __half22float2(hp[1]);
        const float2 f2 = __half22float2(hp[2]);
        const float2 f3 = __half22float2(hp[3]);
        hv[0] = fmaxf(fmaf(f0.x, ssl[c0 + 0], ssl[64 + c0 + 0]), 0.f);
        hv[1] = fmaxf(fmaf(f0.y, ssl[c0 + 1], ssl[64 + c0 + 1]), 0.f);
        hv[2] = fmaxf(fmaf(f1.x, ssl[c0 + 2], ssl[64 + c0 + 2]), 0.f);
        hv[3] = fmaxf(fmaf(f1.y, ssl[c0 + 3], ssl[64 + c0 + 3]), 0.f);
        hv[4] = fmaxf(fmaf(f2.x, ssl[c0 + 4], ssl[64 + c0 + 4]), 0.f);
        hv[5] = fmaxf(fmaf(f2.y, ssl[c0 + 5], ssl[64 + c0 + 5]), 0.f);
        hv[6] = fmaxf(fmaf(f3.x, ssl[c0 + 6], ssl[64 + c0 + 6]), 0.f);
        hv[7] = fmaxf(fmaf(f3.y, ssl[c0 + 7], ssl[64 + c0 + 7]), 0.f);
      }
      if (WMODE == 1) {
        *(float4*)&hout[n * HH + c0] = make_float4(hv[0], hv[1], hv[2], hv[3]);
        *(float4*)&hout[n * HH + c0 + 4] = make_float4(hv[4], hv[5], hv[6], hv[7]);
      } else {
        const __half2 p0 = __floats2half2_rn(hv[0], hv[1]);
        const __half2 p1 = __floats2half2_rn(hv[2], hv[3]);
        const __half2 p2 = __floats2half2_rn(hv[4], hv[5]);
        const __half2 p3 = __floats2half2_rn(hv[6], hv[7]);
        int4 pk;
        pk.x = *(const int*)&p0; pk.y = *(const int*)&p1;
        pk.z = *(const int*)&p2; pk.w = *(const int*)&p3;
        *(int4*)&h16out[n * HH + c0] = pk;
      }
      float rr[8] = {0, 0, 0, 0, 0, 0, 0, 0};
#pragma unroll
      for (int j = 0; j < 8; ++j) {
        const float a = hv[j];
        const int k = c0 + j;
#pragma unroll
        for (int u = 0; u < 8; ++u) rr[u] = fmaf(a, Wl[k * 9 + u], rr[u]);
      }
      float s4[4];
#pragma unroll
      for (int i = 0; i < 4; ++i) {
        const float keepv = b0 ? rr[2 * i + 1] : rr[2 * i];
        const float send = b0 ? rr[2 * i] : rr[2 * i + 1];
        s4[i] = keepv + __shfl_xor(send, 1);
      }
      float s2[2];
#pragma unroll
      for (int i = 0; i < 2; ++i) {
        const float keepv = b1 ? s4[2 * i + 1] : s4[2 * i];
        const float send = b1 ? s4[2 * i] : s4[2 * i + 1];
        s2[i] = keepv + __shfl_xor(send, 2);
      }
      const float keepv = b2 ? s2[1] : s2[0];
      const float send = b2 ? s2[0] : s2[1];
      const float v = keepv + __shfl_xor(send, 4) + lb[t & 7];
      const int g = batch[n];
      const int gidx = g - gfirst;
      const unsigned ev = enc_f32(v);
      if (gidx < 8)
        atomicMax(&smax[gidx][t & 7], ev);
      else
        atomicMax(&outmax[g * 8 + (t & 7)], ev);
    }
  }
  __syncthreads();
  if (t < 64) {
    const unsigned vv = smax[t >> 3][t & 7];
    if (vv) atomicMax(&outmax[(gfirst + (t >> 3)) * 8 + (t & 7)], vv);
  }
}

__global__ void combine_kernel(const unsigned* __restrict__ outmax,
                               float* __restrict__ out) {
  const int i = blockIdx.x * 64 + threadIdx.x;  // 8 x 64 = 512
  float s = 0.f;
#pragma unroll
  for (int l = 0; l < 4; ++l) s += dec_f32(outmax[l * GG * TT + i]);
  out[i] = s;
}

extern "C" void kernel_launch(void* const* d_in, const int* in_sizes, int n_in,
                              void* d_out, int out_size, void* d_ws,
                              size_t ws_size, hipStream_t stream) {
  const float* x      = (const float*)d_in[0];
  const int*   ei     = (const int*)d_in[1];
  const int*   batch  = (const int*)d_in[2];
  const float* fh_W1  = (const float*)d_in[3];
  const float* fh_b1  = (const float*)d_in[4];
  const float* fh_g1  = (const float*)d_in[5];
  const float* fh_be1 = (const float*)d_in[6];
  const float* fh_W2  = (const float*)d_in[7];
  const float* fh_b2  = (const float*)d_in[8];
  const float* fh_g2  = (const float*)d_in[9];
  const float* fh_be2 = (const float*)d_in[10];
  const float* cv_W1  = (const float*)d_in[11];
  const float* cv_b1  = (const float*)d_in[12];
  const float* cv_g1  = (const float*)d_in[13];
  const float* cv_be1 = (const float*)d_in[14];
  const float* cv_W2  = (const float*)d_in[15];
  const float* cv_b2  = (const float*)d_in[16];
  const float* cv_g2  = (const float*)d_in[17];
  const float* cv_be2 = (const float*)d_in[18];
  const float* lin_W  = (const float*)d_in[19];
  const float* lin_b  = (const float*)d_in[20];

  float* out = (float*)d_out;  // [64,8]
  float* h = out + GG * TT;    // [N,64] fp32 final h (written by last readout)

  char* w = (char*)d_ws;
  float* stats = (float*)w;                       w += 8 * 128 * 4;   // 8 slots
  unsigned* outmax = (unsigned*)w;                w += 4 * GG * TT * 4;
  int* bcnt = (int*)w;                            w += 256 * 4;
  int* bbase = (int*)w;                           w += 256 * 4;
  int* bcur = (int*)w;                            w += 256 * 4;
  int* offs = (int*)w;                            w += (NN + 1) * 4;
  int* srcs = (int*)w;                            w += (size_t)EE * 4;
  w = (char*)(((size_t)w + 15) & ~(size_t)15);
  __half* h16 = (__half*)w;                       w += (size_t)NN * HH * 2;
  __half* y1 = (__half*)w;                        w += (size_t)NN * HH * 2;
  __half* y2 = (__half*)w;                        w += (size_t)NN * HH * 2;
  w = (char*)(((size_t)w + 15) & ~(size_t)15);
  float* agg = (float*)w;                         w += (size_t)NN * HH * 4;
  unsigned long long* ebuf = (unsigned long long*)agg;  // alias: ebuf dead
                                                        // before first gather

  const int NBLK = (NN + 63) / 64;             // 782
  const int NRD = (NN + RNODES - 1) / RNODES;  // 391
  const int NGA = (NN * 8 + 255) / 256;        // 1563
  const int NSC = (EE + SCAT_CHUNK - 1) / SCAT_CHUNK;  // 391

  hipMemsetAsync(stats, 0, (8 * 128 + 4 * GG * TT) * sizeof(float), stream);
  hipMemsetAsync(bcnt, 0, 256 * sizeof(int), stream);

  // ---- bucketed CSR build ----
  bcount_kernel<<<512, 256, 0, stream>>>(ei, bcnt);
  bscan_kernel<<<1, 256, 0, stream>>>(bcnt, bbase, bcur);
  bscatter_kernel<<<NSC, 256, 0, stream>>>(ei, bcur, ebuf);
  bcsr_kernel<<<NBKT, 256, 0, stream>>>(bbase, ebuf, offs, srcs);

  // ---- first_h ----
  mm_stats_kernel<FIN, 0><<<NBLK, 256, 0, stream>>>(
      x, nullptr, nullptr, nullptr, nullptr, nullptr, fh_W1, fh_b1, y1, stats);
  mm_stats_kernel<HH, 1><<<NBLK, 256, 0, stream>>>(
      nullptr, y1, nullptr, stats, fh_g1, fh_be1, fh_W2, fh_b2, y2, stats + 128);
  bnrelu_readout_kernel<0><<<NRD, 256, 0, stream>>>(
      y2, stats + 128, fh_g2, fh_be2, h, h16, lin_W, lin_b, batch, outmax);

  // ---- GIN conv layers ----
  for (int l = 0; l < NCONVS; ++l) {
    float* s1 = stats + (2 + 2 * l) * 128;
    float* s2 = stats + (3 + 2 * l) * 128;
    gather16_kernel<<<NGA, 256, 0, stream>>>(offs, srcs, h16, agg);
    mm_stats_kernel<HH, 2><<<NBLK, 256, 0, stream>>>(
        nullptr, h16, agg, nullptr, nullptr, nullptr,
        cv_W1 + l * HH * HH, cv_b1 + l * HH, y1, s1);
    mm_stats_kernel<HH, 1><<<NBLK, 256, 0, stream>>>(
        nullptr, y1, nullptr, s1, cv_g1 + l * HH, cv_be1 + l * HH,
        cv_W2 + l * HH * HH, cv_b2 + l * HH, y2, s2);
    if (l == NCONVS - 1) {
      bnrelu_readout_kernel<1><<<NRD, 256, 0, stream>>>(
          y2, s2, cv_g2 + l * HH, cv_be2 + l * HH, h, h16,
          lin_W + (l + 1) * HH * TT, lin_b + (l + 1) * TT, batch,
          outmax + (l + 1) * GG * TT);
    } else {
      bnrelu_readout_kernel<0><<<NRD, 256, 0, stream>>>(
          y2, s2, cv_g2 + l * HH, cv_be2 + l * HH, h, h16,
          lin_W + (l + 1) * HH * TT, lin_b + (l + 1) * TT, batch,
          outmax + (l + 1) * GG * TT);
    }
  }
  combine_kernel<<<8, 64, 0, stream>>>(outmax, out);
}

// Round 7
// 362.315 us; speedup vs baseline: 1.3253x; 1.1236x over previous
//
#include <hip/hip_runtime.h>
#include <hip/hip_fp16.h>

#define NN 50000
#define EE 800000
#define FIN 128
#define HH 64
#define TT 8
#define GG 64
#define NCONVS 3
#define BN_EPS 1e-5f
#define RNODES 128            // nodes per readout block
#define NBKT 196              // ceil(NN/256) buckets of 256 nodes
#define SCAT_CHUNK 2048       // edges per bscatter block

__device__ __forceinline__ unsigned enc_f32(float x) {
  unsigned u = __float_as_uint(x);
  return (u & 0x80000000u) ? ~u : (u | 0x80000000u);
}
__device__ __forceinline__ float dec_f32(unsigned e) {
  unsigned u = (e & 0x80000000u) ? (e & 0x7fffffffu) : ~e;
  return __uint_as_float(u);
}

// y16[N,64] = op(...) @ W[K,64] + bias (fp16 out), fused fp32 BN stats.
// MODE 0: in = raw fp32 (K=FIN)
// MODE 1: relu(hin*scale+shift), hin fp16, scale/shift from stats_in
// MODE 2: hin[row] (fp16 h) + agg[row] (fp16)
// Block: 64 rows. Thread: 4 rows x 4 cols (A-tile transposed in LDS).
template <int K, int MODE>
__global__ __launch_bounds__(256) void mm_stats_kernel(
    const float* __restrict__ in, const __half* __restrict__ hin,
    const __half* __restrict__ agg, const float* __restrict__ stats_in,
    const float* __restrict__ gamma, const float* __restrict__ beta,
    const float* __restrict__ W, const float* __restrict__ bias,
    __half* __restrict__ y16, float* __restrict__ stats_out) {
  constexpr int NPH = K / 64;
  __shared__ float Wl[K * HH];
  __shared__ float AT[64 * 68];   // AT[kl][row], stride 68 (16B-aligned rows)
  __shared__ float ssl[128];
  __shared__ float sred[4][128];
  const int t = threadIdx.x;
  if (MODE == 1) {
    if (t < 64) {
      const float inv = 1.f / (float)NN;
      const float mean = stats_in[t] * inv;
      const float var = stats_in[64 + t] * inv - mean * mean;
      const float sc = gamma[t] * rsqrtf(var + BN_EPS);
      ssl[t] = sc;
      ssl[64 + t] = fmaf(-mean, sc, beta[t]);
    }
    __syncthreads();
  }
  {
    const float4* W4 = (const float4*)W;
    float4* Wl4 = (float4*)Wl;
#pragma unroll
    for (int i = 0; i < (K * HH) / 1024; ++i) Wl4[t + i * 256] = W4[t + i * 256];
  }
  const int srow = t >> 2, scq = t & 3;          // staging: row, col-quarter
  const int grow_s = blockIdx.x * 64 + srow;
  const int g4 = (t & 15) * 4;                    // compute: 4 cols
  const int r0 = (t >> 4) * 4;                    // compute: 4 rows (local)
  const int row0 = blockIdx.x * 64 + r0;
  const float4 bb = *(const float4*)&bias[g4];
  float4 acc0 = make_float4(0, 0, 0, 0), acc1 = make_float4(0, 0, 0, 0);
  float4 acc2 = make_float4(0, 0, 0, 0), acc3 = make_float4(0, 0, 0, 0);

#pragma unroll
  for (int p = 0; p < NPH; ++p) {
    if (p > 0) __syncthreads();  // protect AT restage vs previous compute
    if (MODE == 0) {
      if (grow_s < NN) {
#pragma unroll
        for (int i = 0; i < 4; ++i) {
          const int kl = scq * 16 + i * 4;
          const float4 v = *(const float4*)&in[(size_t)grow_s * K + p * 64 + kl];
          AT[(kl + 0) * 68 + srow] = v.x;
          AT[(kl + 1) * 68 + srow] = v.y;
          AT[(kl + 2) * 68 + srow] = v.z;
          AT[(kl + 3) * 68 + srow] = v.w;
        }
      } else {
#pragma unroll
        for (int i = 0; i < 16; ++i) AT[(scq * 16 + i) * 68 + srow] = 0.f;
      }
    } else {
      if (grow_s < NN) {
#pragma unroll
        for (int q = 0; q < 2; ++q) {
          const int kl = scq * 16 + q * 8;
          const int4 rv = *(const int4*)&hin[grow_s * HH + kl];
          const __half2* hp = (const __half2*)&rv;
          const float2 f0 = __half22float2(hp[0]);
          const float2 f1 = __half22float2(hp[1]);
          const float2 f2 = __half22float2(hp[2]);
          const float2 f3 = __half22float2(hp[3]);
          float f[8] = {f0.x, f0.y, f1.x, f1.y, f2.x, f2.y, f3.x, f3.y};
          if (MODE == 2) {
            const int4 av = *(const int4*)&agg[grow_s * HH + kl];
            const __half2* ap = (const __half2*)&av;
            const float2 a0 = __half22float2(ap[0]);
            const float2 a1 = __half22float2(ap[1]);
            const float2 a2 = __half22float2(ap[2]);
            const float2 a3 = __half22float2(ap[3]);
            f[0] += a0.x; f[1] += a0.y; f[2] += a1.x; f[3] += a1.y;
            f[4] += a2.x; f[5] += a2.y; f[6] += a3.x; f[7] += a3.y;
          } else {  // MODE 1: bn+relu at staging
#pragma unroll
            for (int j = 0; j < 8; ++j)
              f[j] = fmaxf(fmaf(f[j], ssl[kl + j], ssl[64 + kl + j]), 0.f);
          }
#pragma unroll
          for (int j = 0; j < 8; ++j) AT[(kl + j) * 68 + srow] = f[j];
        }
      } else {
#pragma unroll
        for (int i = 0; i < 16; ++i) AT[(scq * 16 + i) * 68 + srow] = 0.f;
      }
    }
    __syncthreads();
#pragma unroll 8
    for (int kl = 0; kl < 64; ++kl) {
      const float4 w = *(const float4*)&Wl[(p * 64 + kl) * HH + g4];
      const float4 a = *(const float4*)&AT[kl * 68 + r0];
      acc0.x = fmaf(a.x, w.x, acc0.x); acc0.y = fmaf(a.x, w.y, acc0.y);
      acc0.z = fmaf(a.x, w.z, acc0.z); acc0.w = fmaf(a.x, w.w, acc0.w);
      acc1.x = fmaf(a.y, w.x, acc1.x); acc1.y = fmaf(a.y, w.y, acc1.y);
      acc1.z = fmaf(a.y, w.z, acc1.z); acc1.w = fmaf(a.y, w.w, acc1.w);
      acc2.x = fmaf(a.z, w.x, acc2.x); acc2.y = fmaf(a.z, w.y, acc2.y);
      acc2.z = fmaf(a.z, w.z, acc2.z); acc2.w = fmaf(a.z, w.w, acc2.w);
      acc3.x = fmaf(a.w, w.x, acc3.x); acc3.y = fmaf(a.w, w.y, acc3.y);
      acc3.z = fmaf(a.w, w.z, acc3.z); acc3.w = fmaf(a.w, w.w, acc3.w);
    }
  }
  // epilogue: bias, fp16 write, per-thread stats over the 4 owned rows
  float st_s[4] = {0.f, 0.f, 0.f, 0.f}, st_q[4] = {0.f, 0.f, 0.f, 0.f};
#pragma unroll
  for (int ri = 0; ri < 4; ++ri) {
    const int grow = row0 + ri;
    if (grow < NN) {
      const float4 ac = (ri == 0) ? acc0 : (ri == 1) ? acc1 : (ri == 2) ? acc2 : acc3;
      float4 o;
      o.x = ac.x + bb.x; o.y = ac.y + bb.y; o.z = ac.z + bb.z; o.w = ac.w + bb.w;
      const __half2 p0 = __floats2half2_rn(o.x, o.y);
      const __half2 p1 = __floats2half2_rn(o.z, o.w);
      int2 pk;
      pk.x = *(const int*)&p0; pk.y = *(const int*)&p1;
      *(int2*)&y16[grow * HH + g4] = pk;
      st_s[0] += o.x; st_s[1] += o.y; st_s[2] += o.z; st_s[3] += o.w;
      st_q[0] = fmaf(o.x, o.x, st_q[0]); st_q[1] = fmaf(o.y, o.y, st_q[1]);
      st_q[2] = fmaf(o.z, o.z, st_q[2]); st_q[3] = fmaf(o.w, o.w, st_q[3]);
    }
  }
#pragma unroll
  for (int off = 16; off <= 32; off <<= 1) {
#pragma unroll
    for (int i = 0; i < 4; ++i) {
      st_s[i] += __shfl_xor(st_s[i], off);
      st_q[i] += __shfl_xor(st_q[i], off);
    }
  }
  const int wave = t >> 6, lane = t & 63;
  if (lane < 16) {
#pragma unroll
    for (int i = 0; i < 4; ++i) {
      sred[wave][lane * 4 + i] = st_s[i];
      sred[wave][64 + lane * 4 + i] = st_q[i];
    }
  }
  __syncthreads();
  if (t < 128)
    atomicAdd(&stats_out[t],
              sred[0][t] + sred[1][t] + sred[2][t] + sred[3][t]);
}

// ---------------- bucketed CSR build ----------------
__global__ __launch_bounds__(256) void bcount_kernel(const int* __restrict__ ei,
                                                     int* __restrict__ bcnt) {
  __shared__ int l[256];
  const int t = threadIdx.x;
  l[t] = 0;
  __syncthreads();
  for (int e = blockIdx.x * 256 + t; e < EE; e += gridDim.x * 256)
    atomicAdd(&l[ei[EE + e] >> 8], 1);
  __syncthreads();
  if (t < NBKT && l[t]) atomicAdd(&bcnt[t], l[t]);
}

__global__ void bscan_kernel(const int* __restrict__ bcnt,
                             int* __restrict__ bbase, int* __restrict__ bcur) {
  __shared__ int s[256];
  const int t = threadIdx.x;
  const int v = (t < NBKT) ? bcnt[t] : 0;
  s[t] = v;
  __syncthreads();
  for (int off = 1; off < 256; off <<= 1) {
    const int u = (t >= off) ? s[t - off] : 0;
    __syncthreads();
    s[t] += u;
    __syncthreads();
  }
  const int excl = s[t] - v;
  if (t < NBKT) {
    bbase[t] = excl;
    bcur[t] = excl;
  }
  if (t == 255) bbase[NBKT] = s[255];  // == EE
}

__global__ __launch_bounds__(256) void bscatter_kernel(
    const int* __restrict__ ei, int* __restrict__ bcur,
    unsigned long long* __restrict__ ebuf) {
  __shared__ int lcnt[256];
  __shared__ int lbase[256];
  const int t = threadIdx.x;
  lcnt[t] = 0;
  __syncthreads();
  const int e0 = blockIdx.x * SCAT_CHUNK;
  int mysrc[8], mydl[8], mybkt[8], myloc[8];
#pragma unroll
  for (int i = 0; i < 8; ++i) {
    const int e = e0 + i * 256 + t;
    if (e < EE) {
      const int dst = ei[EE + e];
      mybkt[i] = dst >> 8;
      mydl[i] = dst & 255;
      mysrc[i] = ei[e];
      myloc[i] = atomicAdd(&lcnt[mybkt[i]], 1);
    } else {
      mybkt[i] = -1;
    }
  }
  __syncthreads();
  if (t < NBKT && lcnt[t]) lbase[t] = atomicAdd(&bcur[t], lcnt[t]);
  __syncthreads();
#pragma unroll
  for (int i = 0; i < 8; ++i) {
    if (mybkt[i] >= 0) {
      const int pos = lbase[mybkt[i]] + myloc[i];
      ebuf[pos] = ((unsigned long long)(unsigned)mydl[i] << 32) |
                  (unsigned)mysrc[i];
    }
  }
}

__global__ __launch_bounds__(256) void bcsr_kernel(
    const int* __restrict__ bbase, const unsigned long long* __restrict__ ebuf,
    int* __restrict__ offs, int* __restrict__ srcs) {
  __shared__ int ldeg[256];
  __shared__ int sscan[256];
  __shared__ int lcur[256];
  const int t = threadIdx.x;
  const int b = blockIdx.x;
  const int e0 = bbase[b], e1 = bbase[b + 1];
  ldeg[t] = 0;
  __syncthreads();
  for (int e = e0 + t; e < e1; e += 256)
    atomicAdd(&ldeg[(int)(ebuf[e] >> 32)], 1);
  __syncthreads();
  const int v = ldeg[t];
  sscan[t] = v;
  __syncthreads();
  for (int off = 1; off < 256; off <<= 1) {
    const int u = (t >= off) ? sscan[t - off] : 0;
    __syncthreads();
    sscan[t] += u;
    __syncthreads();
  }
  const int excl = sscan[t] - v;
  const int node = b * 256 + t;
  if (node < NN) offs[node] = e0 + excl;
  if (b == NBKT - 1 && t == 0) offs[NN] = EE;
  lcur[t] = e0 + excl;
  __syncthreads();
  for (int e = e0 + t; e < e1; e += 256) {
    const unsigned long long u = ebuf[e];
    const int dl = (int)(u >> 32);
    const int pos = atomicAdd(&lcur[dl], 1);
    srcs[pos] = (int)(u & 0xffffffffu);
  }
}

__device__ __forceinline__ void acc_half8(const int4 r, float4& lo, float4& hi) {
  const __half2* p = (const __half2*)&r;
  const float2 f0 = __half22float2(p[0]);
  const float2 f1 = __half22float2(p[1]);
  const float2 f2 = __half22float2(p[2]);
  const float2 f3 = __half22float2(p[3]);
  lo.x += f0.x; lo.y += f0.y; lo.z += f1.x; lo.w += f1.y;
  hi.x += f2.x; hi.y += f2.y; hi.z += f3.x; hi.w += f3.y;
}

// agg16[n] = sum over CSR neighbors of h16[src]; fp32 accumulate, fp16 store.
__global__ __launch_bounds__(256) void gather16_kernel(
    const int* __restrict__ offs, const int* __restrict__ srcs,
    const __half* __restrict__ h16, __half* __restrict__ agg) {
  const int gid = blockIdx.x * 256 + threadIdx.x;
  const int n = gid >> 3, lane = gid & 7;
  if (n >= NN) return;
  const int c0 = lane * 8;
  const int s0 = offs[n], s1 = offs[n + 1];
  float4 aA0 = make_float4(0, 0, 0, 0), aA1 = make_float4(0, 0, 0, 0);
  float4 aB0 = make_float4(0, 0, 0, 0), aB1 = make_float4(0, 0, 0, 0);
  int j = s0;
  for (; j + 1 < s1; j += 2) {
    const int sA = srcs[j], sB = srcs[j + 1];
    const int4 rA = *(const int4*)&h16[sA * HH + c0];
    const int4 rB = *(const int4*)&h16[sB * HH + c0];
    acc_half8(rA, aA0, aA1);
    acc_half8(rB, aB0, aB1);
  }
  if (j < s1) {
    const int4 rA = *(const int4*)&h16[srcs[j] * HH + c0];
    acc_half8(rA, aA0, aA1);
  }
  aA0.x += aB0.x; aA0.y += aB0.y; aA0.z += aB0.z; aA0.w += aB0.w;
  aA1.x += aB1.x; aA1.y += aB1.y; aA1.z += aB1.z; aA1.w += aB1.w;
  const __half2 p0 = __floats2half2_rn(aA0.x, aA0.y);
  const __half2 p1 = __floats2half2_rn(aA0.z, aA0.w);
  const __half2 p2 = __floats2half2_rn(aA1.x, aA1.y);
  const __half2 p3 = __floats2half2_rn(aA1.z, aA1.w);
  int4 pk;
  pk.x = *(const int*)&p0; pk.y = *(const int*)&p1;
  pk.z = *(const int*)&p2; pk.w = *(const int*)&p3;
  *(int4*)&agg[n * HH + c0] = pk;
}

// h = relu(y2*scale+shift); WMODE 0: write h16 fp16; WMODE 1: write fp32 h.
template <int WMODE>
__global__ __launch_bounds__(256) void bnrelu_readout_kernel(
    const __half* __restrict__ y2, const float* __restrict__ stats_in,
    const float* __restrict__ gamma, const float* __restrict__ beta,
    float* __restrict__ hout, __half* __restrict__ h16out,
    const float* __restrict__ linW, const float* __restrict__ linb,
    const int* __restrict__ batch, unsigned* __restrict__ outmax) {
  __shared__ float Wl[HH * 9];
  __shared__ float lb[8];
  __shared__ float ssl[128];
  __shared__ unsigned smax[8][8];
  const int t = threadIdx.x;
  if (t < 64) {
#pragma unroll
    for (int j = 0; j < 8; ++j) Wl[t * 9 + j] = linW[t * 8 + j];
    const float inv = 1.f / (float)NN;
    const float mean = stats_in[t] * inv;
    const float var = stats_in[64 + t] * inv - mean * mean;
    const float sc = gamma[t] * rsqrtf(var + BN_EPS);
    ssl[t] = sc;
    ssl[64 + t] = fmaf(-mean, sc, beta[t]);
  }
  if (t < 8) lb[t] = linb[t];
  if (t >= 64 && t < 128) smax[(t - 64) >> 3][(t - 64) & 7] = 0u;
  const int gfirst = batch[blockIdx.x * RNODES < NN ? blockIdx.x * RNODES : NN - 1];
  __syncthreads();
  const int nl = t >> 3;
  const int c0 = (t & 7) * 8;
  const int b0 = t & 1, b1 = (t >> 1) & 1, b2 = (t >> 2) & 1;
#pragma unroll
  for (int chunk = 0; chunk < RNODES / 32; ++chunk) {
    const int n = blockIdx.x * RNODES + chunk * 32 + nl;
    if (n < NN) {
      float hv[8];
      {
        const int4 rv = *(const int4*)&y2[n * HH + c0];
        const __half2* hp = (const __half2*)&rv;
        const float2 f0 = __half22float2(hp[0]);
        const float2 f1 = __half22float2(hp[1]);
        const float2 f2 = __half22float2(hp[2]);
        const float2 f3 = __half22float2(hp[3]);
        hv[0] = fmaxf(fmaf(f0.x, ssl[c0 + 0], ssl[64 + c0 + 0]), 0.f);
        hv[1] = fmaxf(fmaf(f0.y, ssl[c0 + 1], ssl[64 + c0 + 1]), 0.f);
        hv[2] = fmaxf(fmaf(f1.x, ssl[c0 + 2], ssl[64 + c0 + 2]), 0.f);
        hv[3] = fmaxf(fmaf(f1.y, ssl[c0 + 3], ssl[64 + c0 + 3]), 0.f);
        hv[4] = fmaxf(fmaf(f2.x, ssl[c0 + 4], ssl[64 + c0 + 4]), 0.f);
        hv[5] = fmaxf(fmaf(f2.y, ssl[c0 + 5], ssl[64 + c0 + 5]), 0.f);
        hv[6] = fmaxf(fmaf(f3.x, ssl[c0 + 6], ssl[64 + c0 + 6]), 0.f);
        hv[7] = fmaxf(fmaf(f3.y, ssl[c0 + 7], ssl[64 + c0 + 7]), 0.f);
      }
      if (WMODE == 1) {
        *(float4*)&hout[n * HH + c0] = make_float4(hv[0], hv[1], hv[2], hv[3]);
        *(float4*)&hout[n * HH + c0 + 4] = make_float4(hv[4], hv[5], hv[6], hv[7]);
      } else {
        const __half2 p0 = __floats2half2_rn(hv[0], hv[1]);
        const __half2 p1 = __floats2half2_rn(hv[2], hv[3]);
        const __half2 p2 = __floats2half2_rn(hv[4], hv[5]);
        const __half2 p3 = __floats2half2_rn(hv[6], hv[7]);
        int4 pk;
        pk.x = *(const int*)&p0; pk.y = *(const int*)&p1;
        pk.z = *(const int*)&p2; pk.w = *(const int*)&p3;
        *(int4*)&h16out[n * HH + c0] = pk;
      }
      float rr[8] = {0, 0, 0, 0, 0, 0, 0, 0};
#pragma unroll
      for (int j = 0; j < 8; ++j) {
        const float a = hv[j];
        const int k = c0 + j;
#pragma unroll
        for (int u = 0; u < 8; ++u) rr[u] = fmaf(a, Wl[k * 9 + u], rr[u]);
      }
      float s4[4];
#pragma unroll
      for (int i = 0; i < 4; ++i) {
        const float keepv = b0 ? rr[2 * i + 1] : rr[2 * i];
        const float send = b0 ? rr[2 * i] : rr[2 * i + 1];
        s4[i] = keepv + __shfl_xor(send, 1);
      }
      float s2[2];
#pragma unroll
      for (int i = 0; i < 2; ++i) {
        const float keepv = b1 ? s4[2 * i + 1] : s4[2 * i];
        const float send = b1 ? s4[2 * i] : s4[2 * i + 1];
        s2[i] = keepv + __shfl_xor(send, 2);
      }
      const float keepv = b2 ? s2[1] : s2[0];
      const float send = b2 ? s2[0] : s2[1];
      const float v = keepv + __shfl_xor(send, 4) + lb[t & 7];
      const int g = batch[n];
      const int gidx = g - gfirst;
      const unsigned ev = enc_f32(v);
      if (gidx < 8)
        atomicMax(&smax[gidx][t & 7], ev);
      else
        atomicMax(&outmax[g * 8 + (t & 7)], ev);
    }
  }
  __syncthreads();
  if (t < 64) {
    const unsigned vv = smax[t >> 3][t & 7];
    if (vv) atomicMax(&outmax[(gfirst + (t >> 3)) * 8 + (t & 7)], vv);
  }
}

__global__ void combine_kernel(const unsigned* __restrict__ outmax,
                               float* __restrict__ out) {
  const int i = blockIdx.x * 64 + threadIdx.x;  // 8 x 64 = 512
  float s = 0.f;
#pragma unroll
  for (int l = 0; l < 4; ++l) s += dec_f32(outmax[l * GG * TT + i]);
  out[i] = s;
}

extern "C" void kernel_launch(void* const* d_in, const int* in_sizes, int n_in,
                              void* d_out, int out_size, void* d_ws,
                              size_t ws_size, hipStream_t stream) {
  const float* x      = (const float*)d_in[0];
  const int*   ei     = (const int*)d_in[1];
  const int*   batch  = (const int*)d_in[2];
  const float* fh_W1  = (const float*)d_in[3];
  const float* fh_b1  = (const float*)d_in[4];
  const float* fh_g1  = (const float*)d_in[5];
  const float* fh_be1 = (const float*)d_in[6];
  const float* fh_W2  = (const float*)d_in[7];
  const float* fh_b2  = (const float*)d_in[8];
  const float* fh_g2  = (const float*)d_in[9];
  const float* fh_be2 = (const float*)d_in[10];
  const float* cv_W1  = (const float*)d_in[11];
  const float* cv_b1  = (const float*)d_in[12];
  const float* cv_g1  = (const float*)d_in[13];
  const float* cv_be1 = (const float*)d_in[14];
  const float* cv_W2  = (const float*)d_in[15];
  const float* cv_b2  = (const float*)d_in[16];
  const float* cv_g2  = (const float*)d_in[17];
  const float* cv_be2 = (const float*)d_in[18];
  const float* lin_W  = (const float*)d_in[19];
  const float* lin_b  = (const float*)d_in[20];

  float* out = (float*)d_out;  // [64,8]
  float* h = out + GG * TT;    // [N,64] fp32 final h (written by last readout)

  char* w = (char*)d_ws;
  float* stats = (float*)w;                       w += 8 * 128 * 4;   // 8 slots
  unsigned* outmax = (unsigned*)w;                w += 4 * GG * TT * 4;
  int* bcnt = (int*)w;                            w += 256 * 4;
  int* bbase = (int*)w;                           w += 256 * 4;
  int* bcur = (int*)w;                            w += 256 * 4;
  int* offs = (int*)w;                            w += (NN + 1) * 4;
  int* srcs = (int*)w;                            w += (size_t)EE * 4;
  w = (char*)(((size_t)w + 15) & ~(size_t)15);
  __half* h16 = (__half*)w;                       w += (size_t)NN * HH * 2;
  __half* y1 = (__half*)w;                        w += (size_t)NN * HH * 2;
  __half* y2 = (__half*)w;                        w += (size_t)NN * HH * 2;
  w = (char*)(((size_t)w + 15) & ~(size_t)15);
  __half* agg = (__half*)w;                       w += (size_t)NN * HH * 2;
  unsigned long long* ebuf = (unsigned long long*)agg;  // EE*8 == NN*HH*2 bytes;
                                                        // ebuf dead before gather

  const int NBLK = (NN + 63) / 64;             // 782
  const int NRD = (NN + RNODES - 1) / RNODES;  // 391
  const int NGA = (NN * 8 + 255) / 256;        // 1563
  const int NSC = (EE + SCAT_CHUNK - 1) / SCAT_CHUNK;  // 391

  hipMemsetAsync(stats, 0, (8 * 128 + 4 * GG * TT) * sizeof(float), stream);
  hipMemsetAsync(bcnt, 0, 256 * sizeof(int), stream);

  // ---- bucketed CSR build ----
  bcount_kernel<<<512, 256, 0, stream>>>(ei, bcnt);
  bscan_kernel<<<1, 256, 0, stream>>>(bcnt, bbase, bcur);
  bscatter_kernel<<<NSC, 256, 0, stream>>>(ei, bcur, ebuf);
  bcsr_kernel<<<NBKT, 256, 0, stream>>>(bbase, ebuf, offs, srcs);

  // ---- first_h ----
  mm_stats_kernel<FIN, 0><<<NBLK, 256, 0, stream>>>(
      x, nullptr, nullptr, nullptr, nullptr, nullptr, fh_W1, fh_b1, y1, stats);
  mm_stats_kernel<HH, 1><<<NBLK, 256, 0, stream>>>(
      nullptr, y1, nullptr, stats, fh_g1, fh_be1, fh_W2, fh_b2, y2, stats + 128);
  bnrelu_readout_kernel<0><<<NRD, 256, 0, stream>>>(
      y2, stats + 128, fh_g2, fh_be2, h, h16, lin_W, lin_b, batch, outmax);

  // ---- GIN conv layers ----
  for (int l = 0; l < NCONVS; ++l) {
    float* s1 = stats + (2 + 2 * l) * 128;
    float* s2 = stats + (3 + 2 * l) * 128;
    gather16_kernel<<<NGA, 256, 0, stream>>>(offs, srcs, h16, agg);
    mm_stats_kernel<HH, 2><<<NBLK, 256, 0, stream>>>(
        nullptr, h16, agg, nullptr, nullptr, nullptr,
        cv_W1 + l * HH * HH, cv_b1 + l * HH, y1, s1);
    mm_stats_kernel<HH, 1><<<NBLK, 256, 0, stream>>>(
        nullptr, y1, nullptr, s1, cv_g1 + l * HH, cv_be1 + l * HH,
        cv_W2 + l * HH * HH, cv_b2 + l * HH, y2, s2);
    if (l == NCONVS - 1) {
      bnrelu_readout_kernel<1><<<NRD, 256, 0, stream>>>(
          y2, s2, cv_g2 + l * HH, cv_be2 + l * HH, h, h16,
          lin_W + (l + 1) * HH * TT, lin_b + (l + 1) * TT, batch,
          outmax + (l + 1) * GG * TT);
    } else {
      bnrelu_readout_kernel<0><<<NRD, 256, 0, stream>>>(
          y2, s2, cv_g2 + l * HH, cv_be2 + l * HH, h, h16,
          lin_W + (l + 1) * HH * TT, lin_b + (l + 1) * TT, batch,
          outmax + (l + 1) * GG * TT);
    }
  }
  combine_kernel<<<8, 64, 0, stream>>>(outmax, out);
}